// Round 6
// baseline (132.252 us; speedup 1.0000x reference)
//
#include <hip/hip_runtime.h>
#include <hip/hip_bf16.h>

// Problem constants
constexpr int NN    = 4096;     // nodes
constexpr int EE    = 131072;   // edges
constexpr int IN_F  = 256;
constexpr int OUT_F = 64;
constexpr int HH    = 8;
constexpr int HF    = OUT_F * HH;   // 512
constexpr int CAP   = 128;          // CSR capacity (raw deg: mean 32, 17-sigma < 128)

// f32 -> bf16 round-to-nearest-even
__device__ __forceinline__ unsigned short f2b(float f) {
    unsigned int u = __float_as_uint(f);
    u = u + 0x7FFFu + ((u >> 16) & 1u);
    return (unsigned short)(u >> 16);
}
// bf16 (as u16) -> f32 (exact)
__device__ __forceinline__ float b2f(unsigned int lo16) {
    return __uint_as_float(lo16 << 16);
}

// ---------------------------------------------------------------------------
// K1: fused  Whb(bf16) = x @ W  +  alpha_src/dst  +  column-sums S(fp32)
// tile 64x64, 256 threads, 4x4 microtile, BK=32, register double-buffer.
// ---------------------------------------------------------------------------
#define TM 64
#define TN 64
#define TK 32

__global__ __launch_bounds__(256) void gemm_fused(const float* __restrict__ x,
                                                  const float* __restrict__ W,
                                                  const float* __restrict__ a,
                                                  unsigned short* __restrict__ Whb,
                                                  float* __restrict__ asrc,
                                                  float* __restrict__ adst,
                                                  float* __restrict__ S) {
    __shared__ float As[TK][TM + 4];
    __shared__ float Bs[TK][TN + 4];
    __shared__ float Scol[TN];
    int t  = threadIdx.x;
    int tx = t & 15;
    int ty = t >> 4;
    int m0 = blockIdx.x * TM;
    int n0 = blockIdx.y * TN;
    float acc[4][4] = {};

    float4 pa[2], pb[2];
    {
#pragma unroll
        for (int i = 0; i < 2; ++i) {
            int flat = i * 256 + t, row = flat >> 3, c4 = flat & 7;
            pa[i] = *(const float4*)(x + (size_t)(m0 + row) * IN_F + c4 * 4);
        }
#pragma unroll
        for (int i = 0; i < 2; ++i) {
            int flat = i * 256 + t, row = flat >> 4, c4 = flat & 15;
            pb[i] = *(const float4*)(W + (size_t)row * HF + n0 + c4 * 4);
        }
    }

    for (int k0 = 0; k0 < IN_F; k0 += TK) {
#pragma unroll
        for (int i = 0; i < 2; ++i) {
            int flat = i * 256 + t, row = flat >> 3, c4 = flat & 7;
            As[c4 * 4 + 0][row] = pa[i].x;
            As[c4 * 4 + 1][row] = pa[i].y;
            As[c4 * 4 + 2][row] = pa[i].z;
            As[c4 * 4 + 3][row] = pa[i].w;
        }
#pragma unroll
        for (int i = 0; i < 2; ++i) {
            int flat = i * 256 + t, row = flat >> 4, c4 = flat & 15;
            *(float4*)(&Bs[row][c4 * 4]) = pb[i];
        }
        __syncthreads();
        if (k0 + TK < IN_F) {
            int kn = k0 + TK;
#pragma unroll
            for (int i = 0; i < 2; ++i) {
                int flat = i * 256 + t, row = flat >> 3, c4 = flat & 7;
                pa[i] = *(const float4*)(x + (size_t)(m0 + row) * IN_F + kn + c4 * 4);
            }
#pragma unroll
            for (int i = 0; i < 2; ++i) {
                int flat = i * 256 + t, row = flat >> 4, c4 = flat & 15;
                pb[i] = *(const float4*)(W + (size_t)(kn + row) * HF + n0 + c4 * 4);
            }
        }
#pragma unroll
        for (int k = 0; k < TK; ++k) {
            float4 a4 = *(const float4*)(&As[k][ty * 4]);
            float4 b4 = *(const float4*)(&Bs[k][tx * 4]);
            float av[4] = {a4.x, a4.y, a4.z, a4.w};
            float bv[4] = {b4.x, b4.y, b4.z, b4.w};
#pragma unroll
            for (int ii = 0; ii < 4; ++ii)
#pragma unroll
                for (int jj = 0; jj < 4; ++jj)
                    acc[ii][jj] += av[ii] * bv[jj];
        }
        __syncthreads();
    }

#pragma unroll
    for (int ii = 0; ii < 4; ++ii) {
        ushort4 v;
        v.x = f2b(acc[ii][0]);
        v.y = f2b(acc[ii][1]);
        v.z = f2b(acc[ii][2]);
        v.w = f2b(acc[ii][3]);
        *(ushort4*)(Whb + (size_t)(m0 + ty * 4 + ii) * HF + n0 + tx * 4) = v;
    }

    // alpha epilogue (fp32-exact)
    int h = n0 >> 6;
    float a1v[4], a2v[4];
#pragma unroll
    for (int jj = 0; jj < 4; ++jj) {
        int f = tx * 4 + jj;
        a1v[jj] = a[f];
        a2v[jj] = a[OUT_F + f];
    }
#pragma unroll
    for (int ii = 0; ii < 4; ++ii) {
        float p1 = 0.f, p2 = 0.f;
#pragma unroll
        for (int jj = 0; jj < 4; ++jj) {
            p1 += acc[ii][jj] * a1v[jj];
            p2 += acc[ii][jj] * a2v[jj];
        }
#pragma unroll
        for (int mask = 1; mask < 16; mask <<= 1) {
            p1 += __shfl_xor(p1, mask);
            p2 += __shfl_xor(p2, mask);
        }
        if (tx == 0) {
            int node = m0 + ty * 4 + ii;
            asrc[node * HH + h] = p1;
            adst[node * HH + h] = p2;
        }
    }

    // column-sum epilogue (fp32-exact)
    if (t < TN) Scol[t] = 0.f;
    __syncthreads();
#pragma unroll
    for (int jj = 0; jj < 4; ++jj) {
        float cs = acc[0][jj] + acc[1][jj] + acc[2][jj] + acc[3][jj];
        atomicAdd(&Scol[tx * 4 + jj], cs);
    }
    __syncthreads();
    if (t < TN) atomicAdd(&S[n0 + t], Scol[t]);
}

// ---------------------------------------------------------------------------
// K2: minimal scatter — raw append (duplicates kept; dedup'd in aggregate).
// Per edge: 2 coalesced reads, 1 atomicAdd, 1 random 4B write.
// ---------------------------------------------------------------------------
__global__ __launch_bounds__(256) void scatter_lite(const int* __restrict__ src,
                                                    const int* __restrict__ dst,
                                                    int* __restrict__ cnt,
                                                    int* __restrict__ csr_dst) {
    int e = blockIdx.x * 256 + threadIdx.x;
    if (e >= EE) return;
    int s = src[e], d = dst[e];
    int pos = atomicAdd(&cnt[s], 1);
    csr_dst[(s << 7) + pos] = d;
}

// ---------------------------------------------------------------------------
// K3: per-node aggregation with in-LDS dedup + staged weights.
// out[i,h,f] = (S[h,f] + sum_unique w*Whb[m,h,f]) / (N + sum_unique w)
// 512 thr = 8 groups x 64 lanes; lane reads uint4 (8 bf16 feats, 16B).
// Dup slots get w=0 (exact: duplicates carry identical values under .set).
// ---------------------------------------------------------------------------
__global__ __launch_bounds__(512) void aggregate_kernel(const unsigned short* __restrict__ Whb,
                                                        const float* __restrict__ asrc,
                                                        const float* __restrict__ adst,
                                                        const float* __restrict__ S,
                                                        const int* __restrict__ cnt,
                                                        const int* __restrict__ csr_dst,
                                                        float* __restrict__ out) {
    __shared__ int           midx[CAP];
    __shared__ unsigned char dupf[CAP];
    __shared__ float         wbuf[CAP * HH];   // 4 KB
    __shared__ float         as_sh[HH];
    __shared__ float         denom[HH];
    __shared__ float         red[8][HF];       // 16 KB
    int i = blockIdx.x;
    int t = threadIdx.x;                       // 0..511
    int deg = cnt[i];
    if (deg > CAP) deg = CAP;

    if (t < HH) as_sh[t] = asrc[i * HH + t];
    for (int j = t; j < deg; j += 512) midx[j] = csr_dst[(i << 7) + j];
    __syncthreads();

    // duplicate scan: slot j is dup iff an earlier slot holds the same index
    for (int j = t; j < deg; j += 512) {
        int m = midx[j];
        unsigned char f = 0;
        for (int k = 0; k < j; ++k)
            if (midx[k] == m) { f = 1; break; }
        dupf[j] = f;
    }
    __syncthreads();

    // staged parallel weight computation: thread per (slot, head)
    for (int idx = t; idx < deg * HH; idx += 512) {
        int sl = idx >> 3, h = idx & 7;
        float w = 0.f;
        if (!dupf[sl]) {
            float xv = as_sh[h] + adst[midx[sl] * HH + h];
            xv = (xv > 0.f) ? xv : 0.2f * xv;      // leaky_relu(., 0.2)
            w = __expf(xv) - 1.f;
        }
        wbuf[idx] = w;
    }
    __syncthreads();

    // per-head denominators
    if (t < 128) {
        int h = t >> 4, ln = t & 15;
        float p = 0.f;
        for (int sl = ln; sl < deg; sl += 16) p += wbuf[sl * HH + h];
#pragma unroll
        for (int mask = 1; mask < 16; mask <<= 1) p += __shfl_xor(p, mask);
        if (ln == 0) denom[h] = (float)NN + p;
    }
    __syncthreads();

    // main gather: 8 groups x 64 lanes, 16B/lane, 1-deep pipeline
    int g = t >> 6;                  // group = wave
    int r = t & 63;                  // lane; features r*8 .. r*8+7
    int h = r >> 3;
    float accv[8] = {};

    int j = g;
    uint4 uC = {0, 0, 0, 0};
    float wC = 0.f;
    if (j < deg) {
        wC = wbuf[j * HH + h];
        uC = *(const uint4*)(Whb + ((size_t)midx[j] << 9) + (r << 3));
    }
    while (j < deg) {
        int jn = j + 8;
        uint4 uN = {0, 0, 0, 0};
        float wN = 0.f;
        if (jn < deg) {
            wN = wbuf[jn * HH + h];
            uN = *(const uint4*)(Whb + ((size_t)midx[jn] << 9) + (r << 3));
        }
        accv[0] += wC * b2f(uC.x & 0xFFFFu);
        accv[1] += wC * b2f(uC.x >> 16);
        accv[2] += wC * b2f(uC.y & 0xFFFFu);
        accv[3] += wC * b2f(uC.y >> 16);
        accv[4] += wC * b2f(uC.z & 0xFFFFu);
        accv[5] += wC * b2f(uC.z >> 16);
        accv[6] += wC * b2f(uC.w & 0xFFFFu);
        accv[7] += wC * b2f(uC.w >> 16);
        uC = uN; wC = wN; j = jn;
    }

    float4 v0 = {accv[0], accv[1], accv[2], accv[3]};
    float4 v1 = {accv[4], accv[5], accv[6], accv[7]};
    *(float4*)(&red[g][r * 8])     = v0;
    *(float4*)(&red[g][r * 8 + 4]) = v1;
    __syncthreads();

    float tot = S[t];
#pragma unroll
    for (int gg = 0; gg < 8; ++gg) tot += red[gg][t];
    out[((size_t)i << 9) + t] = tot / denom[t >> 6];
}

// ---------------------------------------------------------------------------
// launcher
// ---------------------------------------------------------------------------
extern "C" void kernel_launch(void* const* d_in, const int* in_sizes, int n_in,
                              void* d_out, int out_size, void* d_ws, size_t ws_size,
                              hipStream_t stream) {
    const float* x  = (const float*)d_in[0];
    const float* W  = (const float*)d_in[1];
    const float* a  = (const float*)d_in[2];
    const int*   ei = (const int*)d_in[3];
    const int* src = ei;
    const int* dst = ei + EE;
    float* out = (float*)d_out;

    // workspace layout (bytes)
    char* ws = (char*)d_ws;
    unsigned short* Whb = (unsigned short*)(ws + 0);   // 4,194,304
    float* asrc     = (float*)(ws + 4194304);          // 131,072
    float* adst     = (float*)(ws + 4325376);          // 131,072
    int*   csr_dst  = (int*)  (ws + 4456448);          // 2,097,152
    float* S        = (float*)(ws + 6553600);          // 2,048
    int*   cnt      = (int*)  (ws + 6555648);          // 16,384

    // zero S + cnt (contiguous, 18.4 KB)
    hipMemsetAsync(ws + 6553600, 0, 2048 + 16384, stream);

    // K2: CSR raw append (independent of GEMM)
    scatter_lite<<<EE / 256, 256, 0, stream>>>(src, dst, cnt, csr_dst);

    // K1: fused GEMM (bf16 Wh out) + alphas + column sums
    gemm_fused<<<dim3(NN / TM, HF / TN), 256, 0, stream>>>(x, W, a, Whb, asrc, adst, S);

    // K3: aggregation (dedup + weights + gather)
    aggregate_kernel<<<NN, 512, 0, stream>>>(Whb, asrc, adst, S, cnt, csr_dst, out);
}